// Round 7
// baseline (1400.994 us; speedup 1.0000x reference)
//
#include <hip/hip_runtime.h>

#define N_NODES 50000
#define N_EDGES 100000
#define NT 21
#define STEPS 6
#define BPT 80    // blocks per edge-type in k_msg
#define NB 100    // blocks for counting sort
#define EPB 1000  // edges per block (NB*EPB == N_EDGES)

// ---------- helpers ----------
__device__ __forceinline__ float sigm(float x) { return 1.f / (1.f + __expf(-x)); }
__device__ __forceinline__ float tanh_f(float x) {
    float t = __expf(2.f * fabsf(x));
    return copysignf(1.f - 2.f / (t + 1.f), x);
}

// ---------- h0 = relu(node_emb[node_ids] @ proj_W + proj_b) ----------
__global__ __launch_bounds__(256) void k_proj(const int* __restrict__ node_ids,
                                              const float* __restrict__ node_emb,
                                              const float* __restrict__ W,   // [64][32]
                                              const float* __restrict__ b,   // [32]
                                              float* __restrict__ h) {
    int lane = threadIdx.x & 31;
    int n = blockIdx.x * 8 + (threadIdx.x >> 5);
    if (n >= N_NODES) return;
    float w[64];
#pragma unroll
    for (int i = 0; i < 64; ++i) w[i] = W[i * 32 + lane];
    int id = node_ids[n];
    const float* er = node_emb + id * 64;
    float e0 = er[lane];
    float e1 = er[32 + lane];
    float acc = b[lane];
#pragma unroll
    for (int i = 0; i < 32; ++i) acc += __shfl(e0, i, 32) * w[i];
#pragma unroll
    for (int i = 0; i < 32; ++i) acc += __shfl(e1, i, 32) * w[32 + i];
    h[n * 32 + lane] = fmaxf(acc, 0.f);
}

// ---------- W table: 21 matrices, Wt[t][i][o] ----------
__global__ __launch_bounds__(128) void k_wtable(const float* __restrict__ edge_emb, // [21][16]
                                                const float* __restrict__ eW1,      // [16][128]
                                                const float* __restrict__ eb1,      // [128]
                                                const float* __restrict__ eW2,      // [128][1024]
                                                const float* __restrict__ eb2,      // [1024]
                                                float* __restrict__ Wt) {           // [21][1024]
    __shared__ float x[128];
    int t = blockIdx.x >> 3, c = blockIdx.x & 7;
    int tid = threadIdx.x;
    float acc = eb1[tid];
#pragma unroll
    for (int i = 0; i < 16; ++i) acc += edge_emb[t * 16 + i] * eW1[i * 128 + tid];
    x[tid] = fmaxf(acc, 0.f);
    __syncthreads();
    int j = c * 128 + tid;
    float a = eb2[j];
#pragma unroll 8
    for (int i = 0; i < 128; ++i) a += x[i] * eW2[i * 1024 + j];
    Wt[t * 1024 + j] = a;
}

// ---------- one-time GRU weight transpose: WT[i][96] from W[96][32] ----------
__global__ void k_tr(const float* __restrict__ Wih, const float* __restrict__ Whh,
                     float* __restrict__ WTih, float* __restrict__ WThh) {
    int u = blockIdx.x * 256 + threadIdx.x;
    if (u < 3072) {
        int k = u >> 5, i = u & 31;      // source W[k][i]
        WTih[i * 96 + k] = Wih[u];
        WThh[i * 96 + k] = Whh[u];
    }
}

// ---------- counting sort, pass A: per-block LDS histogram ----------
__global__ __launch_bounds__(256) void k_hist(const int* __restrict__ eid,
                                              int* __restrict__ hist) {   // [NB][NT]
    __shared__ int lc[NT];
    if (threadIdx.x < NT) lc[threadIdx.x] = 0;
    __syncthreads();
    int e0 = blockIdx.x * EPB;
#pragma unroll
    for (int k = 0; k < EPB / 256 + 1; ++k) {
        int e = e0 + k * 256 + threadIdx.x;
        if (e < e0 + EPB) atomicAdd(&lc[eid[e]], 1);
    }
    __syncthreads();
    if (threadIdx.x < NT) hist[blockIdx.x * NT + threadIdx.x] = lc[threadIdx.x];
}

// ---------- pass B: per-type prefix over blocks + type base scan (1 tiny block) ----------
__global__ void k_offs(const int* __restrict__ hist,  // [NB][NT]
                       int* __restrict__ offs,        // [NB][NT]
                       int* __restrict__ cnt,         // [NT]
                       int* __restrict__ base) {      // [NT]
    __shared__ int tot[NT];
    int t = threadIdx.x;
    if (t < NT) {
        int run = 0;
        for (int b = 0; b < NB; ++b) { offs[b * NT + t] = run; run += hist[b * NT + t]; }
        tot[t] = run;
        cnt[t] = run;
    }
    __syncthreads();
    if (t == 0) {
        int r = 0;
        for (int tt = 0; tt < NT; ++tt) { base[tt] = r; r += tot[tt]; }
    }
}

// ---------- pass C: scatter edges to perm at precomputed offsets (no global atomics) ----------
__global__ __launch_bounds__(256) void k_fill2(const int* __restrict__ eid,
                                               const int* __restrict__ offs,
                                               const int* __restrict__ base,
                                               int* __restrict__ perm) {
    __shared__ int cur[NT];
    int b = blockIdx.x;
    if (threadIdx.x < NT) cur[threadIdx.x] = base[threadIdx.x] + offs[b * NT + threadIdx.x];
    __syncthreads();
    int e0 = b * EPB;
#pragma unroll
    for (int k = 0; k < EPB / 256 + 1; ++k) {
        int e = e0 + k * 256 + threadIdx.x;
        if (e < e0 + EPB) {
            int r = atomicAdd(&cur[eid[e]], 1);
            perm[r] = e;
        }
    }
}

// ---------- message + scatter: agg[dst] += h[src] @ W[type] ----------
// depth-2 software pipeline: indices 2 iters ahead, h-row 1 iter ahead
__global__ __launch_bounds__(256) void k_msg(const int* __restrict__ perm,
                                             const int* __restrict__ base,
                                             const int* __restrict__ cnt,
                                             const int* __restrict__ src,
                                             const int* __restrict__ dst,
                                             const float* __restrict__ Wt,
                                             const float* __restrict__ h,
                                             float* __restrict__ agg) {
    int t = blockIdx.x / BPT, sub = blockIdx.x % BPT;
    int lane = threadIdx.x & 31, g = threadIdx.x >> 5;
    const float* wp = Wt + t * 1024;
    float w[32];
#pragma unroll
    for (int i = 0; i < 32; ++i) w[i] = wp[i * 32 + lane];
    int n = cnt[t], b0 = base[t];
    const int stride = BPT * 8;
    int idx = sub * 8 + g;

    // prologue: slot0 (compute), slot1 (h in flight), slot2 staged in loop
    bool v0 = idx < n, v1 = (idx + stride) < n;
    int s0 = 0, d0 = 0, s1 = 0, d1 = 0;
    if (v0) { int e = perm[b0 + idx]; s0 = src[e]; d0 = dst[e]; }
    if (v1) { int e = perm[b0 + idx + stride]; s1 = src[e]; d1 = dst[e]; }
    float hv = v0 ? h[s0 * 32 + lane] : 0.f;
    int nextIdx = idx + 2 * stride;

    while (v0) {
        // issue next h row (s1 already resolved) and prefetch indices 2 ahead
        float hvN = 0.f;
        if (v1) hvN = h[s1 * 32 + lane];
        int s2 = 0, d2 = 0;
        bool v2 = nextIdx < n;
        if (v2) { int e = perm[b0 + nextIdx]; s2 = src[e]; d2 = dst[e]; }
        // compute on current (hides the loads above)
        float acc = 0.f;
#pragma unroll
        for (int i = 0; i < 32; ++i) acc += __shfl(hv, i, 32) * w[i];
        atomicAdd(&agg[d0 * 32 + lane], acc);
        // rotate
        s0 = s1; d0 = d1; v0 = v1; hv = hvN;
        s1 = s2; d1 = d2; v1 = v2;
        nextIdx += stride;
    }
}

// ---------- GRU v3: no LDS; weights direct from L1-hot transposed global tables ----------
// 2 nodes/thread, 8 threads/pair (4 feats each); depth-1 pipeline on agg/h chunks;
// h chunk j captured in-loop; agg-zero + h-write at kernel end (all threads of a
// pair are in one wave; stores follow all loads in program order).
__global__ __launch_bounds__(256) void k_gru(const float* __restrict__ WTih,  // [32][96]
                                             const float* __restrict__ WThh,  // [32][96]
                                             const float* __restrict__ bih,   // [96]
                                             const float* __restrict__ bhh,   // [96]
                                             const float* __restrict__ cb,    // [32]
                                             float* __restrict__ agg,
                                             float* __restrict__ h) {
    int gtid = blockIdx.x * 256 + threadIdx.x;
    int p = gtid >> 3;                 // node pair
    if (p >= N_NODES / 2) return;
    int j = gtid & 7, kb = j * 4;      // this thread's 4 output features

    float* a0 = agg + (size_t)(2 * p) * 32;
    float* a1 = a0 + 32;
    float* h0p = h + (size_t)(2 * p) * 32;
    float* h1p = h0p + 32;

    float accR0[4] = {0, 0, 0, 0}, accR1[4] = {0, 0, 0, 0};
    float accZ0[4] = {0, 0, 0, 0}, accZ1[4] = {0, 0, 0, 0};
    float accI0[4] = {0, 0, 0, 0}, accI1[4] = {0, 0, 0, 0};
    float accH0[4] = {0, 0, 0, 0}, accH1[4] = {0, 0, 0, 0};

    float4 hs0f = make_float4(0.f, 0.f, 0.f, 0.f);
    float4 hs1f = make_float4(0.f, 0.f, 0.f, 0.f);

    // depth-1 pipelined chunk loads (static indices after unroll)
    float4 bufA[2], bufB[2], bufC[2], bufD[2];
    bufA[0] = ((const float4*)a0)[0];
    bufB[0] = ((const float4*)a1)[0];
    bufC[0] = ((const float4*)h0p)[0];
    bufD[0] = ((const float4*)h1p)[0];

#pragma unroll
    for (int c = 0; c < 8; ++c) {
        const int cur = c & 1, nxt = cur ^ 1;
        if (c < 7) {
            bufA[nxt] = ((const float4*)a0)[c + 1];
            bufB[nxt] = ((const float4*)a1)[c + 1];
            bufC[nxt] = ((const float4*)h0p)[c + 1];
            bufD[nxt] = ((const float4*)h1p)[c + 1];
        }
        float4 ma = bufA[cur], mb = bufB[cur], ha = bufC[cur], hb = bufD[cur];
        if (c == j) { hs0f = ha; hs1f = hb; }   // capture own h chunk (no re-load)
        float4 cb4 = ((const float4*)cb)[c];
        float m0[4] = {fmaxf(ma.x + cb4.x, 0.f), fmaxf(ma.y + cb4.y, 0.f),
                       fmaxf(ma.z + cb4.z, 0.f), fmaxf(ma.w + cb4.w, 0.f)};
        float m1[4] = {fmaxf(mb.x + cb4.x, 0.f), fmaxf(mb.y + cb4.y, 0.f),
                       fmaxf(mb.z + cb4.z, 0.f), fmaxf(mb.w + cb4.w, 0.f)};
        float h0v[4] = {ha.x, ha.y, ha.z, ha.w};
        float h1v[4] = {hb.x, hb.y, hb.z, hb.w};
#pragma unroll
        for (int e = 0; e < 4; ++e) {
            int i = 4 * c + e;
            const float* wb = WTih + i * 96 + kb;   // L1-hot (24 KB total)
            const float* vb = WThh + i * 96 + kb;
            float4 wiR = *(const float4*)(wb);
            float4 whR = *(const float4*)(vb);
            float4 wiZ = *(const float4*)(wb + 32);
            float4 whZ = *(const float4*)(vb + 32);
            float4 wiN = *(const float4*)(wb + 64);
            float4 whN = *(const float4*)(vb + 64);
            float mi0 = m0[e], mi1 = m1[e], hi0 = h0v[e], hi1 = h1v[e];
            accR0[0] += mi0 * wiR.x + hi0 * whR.x;
            accR0[1] += mi0 * wiR.y + hi0 * whR.y;
            accR0[2] += mi0 * wiR.z + hi0 * whR.z;
            accR0[3] += mi0 * wiR.w + hi0 * whR.w;
            accR1[0] += mi1 * wiR.x + hi1 * whR.x;
            accR1[1] += mi1 * wiR.y + hi1 * whR.y;
            accR1[2] += mi1 * wiR.z + hi1 * whR.z;
            accR1[3] += mi1 * wiR.w + hi1 * whR.w;
            accZ0[0] += mi0 * wiZ.x + hi0 * whZ.x;
            accZ0[1] += mi0 * wiZ.y + hi0 * whZ.y;
            accZ0[2] += mi0 * wiZ.z + hi0 * whZ.z;
            accZ0[3] += mi0 * wiZ.w + hi0 * whZ.w;
            accZ1[0] += mi1 * wiZ.x + hi1 * whZ.x;
            accZ1[1] += mi1 * wiZ.y + hi1 * whZ.y;
            accZ1[2] += mi1 * wiZ.z + hi1 * whZ.z;
            accZ1[3] += mi1 * wiZ.w + hi1 * whZ.w;
            accI0[0] += mi0 * wiN.x;  accH0[0] += hi0 * whN.x;
            accI0[1] += mi0 * wiN.y;  accH0[1] += hi0 * whN.y;
            accI0[2] += mi0 * wiN.z;  accH0[2] += hi0 * whN.z;
            accI0[3] += mi0 * wiN.w;  accH0[3] += hi0 * whN.w;
            accI1[0] += mi1 * wiN.x;  accH1[0] += hi1 * whN.x;
            accI1[1] += mi1 * wiN.y;  accH1[1] += hi1 * whN.y;
            accI1[2] += mi1 * wiN.z;  accH1[2] += hi1 * whN.z;
            accI1[3] += mi1 * wiN.w;  accH1[3] += hi1 * whN.w;
        }
    }

    float hs0[4] = {hs0f.x, hs0f.y, hs0f.z, hs0f.w};
    float hs1[4] = {hs1f.x, hs1f.y, hs1f.z, hs1f.w};

    float out0[4], out1[4];
#pragma unroll
    for (int q = 0; q < 4; ++q) {
        float bR = bih[kb + q] + bhh[kb + q];
        float bZ = bih[32 + kb + q] + bhh[32 + kb + q];
        float biN = bih[64 + kb + q];
        float bhN = bhh[64 + kb + q];
        float r0 = sigm(accR0[q] + bR);
        float z0 = sigm(accZ0[q] + bZ);
        float n0 = tanh_f(accI0[q] + biN + r0 * (accH0[q] + bhN));
        out0[q] = (1.f - z0) * n0 + z0 * hs0[q];
        float r1 = sigm(accR1[q] + bR);
        float z1 = sigm(accZ1[q] + bZ);
        float n1 = tanh_f(accI1[q] + biN + r1 * (accH1[q] + bhN));
        out1[q] = (1.f - z1) * n1 + z1 * hs1[q];
    }

    // zero agg slices for next step, then write h (all after every load)
    float4 z4 = make_float4(0.f, 0.f, 0.f, 0.f);
    ((float4*)a0)[j] = z4;
    ((float4*)a1)[j] = z4;
    ((float4*)h0p)[j] = make_float4(out0[0], out0[1], out0[2], out0[3]);
    ((float4*)h1p)[j] = make_float4(out1[0], out1[1], out1[2], out1[3]);
}

extern "C" void kernel_launch(void* const* d_in, const int* in_sizes, int n_in,
                              void* d_out, int out_size, void* d_ws, size_t ws_size,
                              hipStream_t stream) {
    const int*   node_ids  = (const int*)d_in[0];
    const int*   edge_ids  = (const int*)d_in[1];
    const int*   src       = (const int*)d_in[2];
    const int*   dst       = (const int*)d_in[3];
    const float* node_emb  = (const float*)d_in[4];
    const float* edge_emb  = (const float*)d_in[5];
    const float* proj_W    = (const float*)d_in[6];
    const float* proj_b    = (const float*)d_in[7];
    const float* eW1       = (const float*)d_in[8];
    const float* eb1       = (const float*)d_in[9];
    const float* eW2       = (const float*)d_in[10];
    const float* eb2       = (const float*)d_in[11];
    const float* conv_bias = (const float*)d_in[12];
    const float* gWih      = (const float*)d_in[13];
    const float* gWhh      = (const float*)d_in[14];
    const float* gbih      = (const float*)d_in[15];
    const float* gbhh      = (const float*)d_in[16];

    float* h = (float*)d_out;  // [N,32] fp32 — output buffer doubles as hidden state
    char* ws = (char*)d_ws;
    float* agg  = (float*)ws;                                  // 6,400,000 B
    float* Wt   = (float*)(ws + 6400 * 1024);                  // 86,016 B (< 96 KB)
    float* WTih = (float*)(ws + 6400 * 1024 + 96 * 1024);      // 12,288 B
    float* WThh = (float*)(ws + 6400 * 1024 + 96 * 1024 + 12 * 1024);
    int*   hist = (int*)(ws + 6400 * 1024 + 128 * 1024);       // NB*NT = 2100
    int*   offs = hist + NB * NT;                              // 2100
    int*   cnt  = offs + NB * NT;                              // 32
    int*   base = cnt + 32;                                    // 32
    int*   perm = base + 32;                                   // 100,000

    hipMemsetAsync(agg, 0, (size_t)N_NODES * 32 * sizeof(float), stream);

    k_proj<<<(N_NODES + 7) / 8, 256, 0, stream>>>(node_ids, node_emb, proj_W, proj_b, h);
    k_wtable<<<NT * 8, 128, 0, stream>>>(edge_emb, eW1, eb1, eW2, eb2, Wt);
    k_tr<<<12, 256, 0, stream>>>(gWih, gWhh, WTih, WThh);
    k_hist<<<NB, 256, 0, stream>>>(edge_ids, hist);
    k_offs<<<1, 64, 0, stream>>>(hist, offs, cnt, base);
    k_fill2<<<NB, 256, 0, stream>>>(edge_ids, offs, base, perm);

    for (int s = 0; s < STEPS; ++s) {
        k_msg<<<NT * BPT, 256, 0, stream>>>(perm, base, cnt, src, dst, Wt, h, agg);
        k_gru<<<(N_NODES / 2 * 8 + 255) / 256, 256, 0, stream>>>(WTih, WThh, gbih, gbhh, conv_bias, agg, h);
    }
}

// Round 8
// 581.847 us; speedup vs baseline: 2.4078x; 2.4078x over previous
//
#include <hip/hip_runtime.h>

#define N_NODES 50000
#define N_EDGES 100000
#define NT 21
#define STEPS 6
#define BPT 40    // blocks per edge-type in k_msg
#define NB 100    // blocks for counting sort
#define EPB 1000  // edges per block (NB*EPB == N_EDGES)
#define NPAIRS (N_NODES / 2)
#define GRU_WAVES 2048

// ---------- helpers ----------
__device__ __forceinline__ float sigm(float x) { return 1.f / (1.f + __expf(-x)); }
__device__ __forceinline__ float tanh_f(float x) {
    float t = __expf(2.f * fabsf(x));
    return copysignf(1.f - 2.f / (t + 1.f), x);
}

// ---------- h0 = relu(node_emb[node_ids] @ proj_W + proj_b) ----------
__global__ __launch_bounds__(256) void k_proj(const int* __restrict__ node_ids,
                                              const float* __restrict__ node_emb,
                                              const float* __restrict__ W,   // [64][32]
                                              const float* __restrict__ b,   // [32]
                                              float* __restrict__ h) {
    int lane = threadIdx.x & 31;
    int n = blockIdx.x * 8 + (threadIdx.x >> 5);
    if (n >= N_NODES) return;
    float w[64];
#pragma unroll
    for (int i = 0; i < 64; ++i) w[i] = W[i * 32 + lane];
    int id = node_ids[n];
    const float* er = node_emb + id * 64;
    float e0 = er[lane];
    float e1 = er[32 + lane];
    float acc = b[lane];
#pragma unroll
    for (int i = 0; i < 32; ++i) acc += __shfl(e0, i, 32) * w[i];
#pragma unroll
    for (int i = 0; i < 32; ++i) acc += __shfl(e1, i, 32) * w[32 + i];
    h[n * 32 + lane] = fmaxf(acc, 0.f);
}

// ---------- W table: 21 matrices, Wt[t][i][o] ----------
__global__ __launch_bounds__(128) void k_wtable(const float* __restrict__ edge_emb, // [21][16]
                                                const float* __restrict__ eW1,      // [16][128]
                                                const float* __restrict__ eb1,      // [128]
                                                const float* __restrict__ eW2,      // [128][1024]
                                                const float* __restrict__ eb2,      // [1024]
                                                float* __restrict__ Wt) {           // [21][1024]
    __shared__ float x[128];
    int t = blockIdx.x >> 3, c = blockIdx.x & 7;
    int tid = threadIdx.x;
    float acc = eb1[tid];
#pragma unroll
    for (int i = 0; i < 16; ++i) acc += edge_emb[t * 16 + i] * eW1[i * 128 + tid];
    x[tid] = fmaxf(acc, 0.f);
    __syncthreads();
    int j = c * 128 + tid;
    float a = eb2[j];
#pragma unroll 8
    for (int i = 0; i < 128; ++i) a += x[i] * eW2[i * 1024 + j];
    Wt[t * 1024 + j] = a;
}

// ---------- counting sort, pass A: per-block LDS histogram ----------
__global__ __launch_bounds__(256) void k_hist(const int* __restrict__ eid,
                                              int* __restrict__ hist) {   // [NB][NT]
    __shared__ int lc[NT];
    if (threadIdx.x < NT) lc[threadIdx.x] = 0;
    __syncthreads();
    int e0 = blockIdx.x * EPB;
#pragma unroll
    for (int k = 0; k < EPB / 256 + 1; ++k) {
        int e = e0 + k * 256 + threadIdx.x;
        if (e < e0 + EPB) atomicAdd(&lc[eid[e]], 1);
    }
    __syncthreads();
    if (threadIdx.x < NT) hist[blockIdx.x * NT + threadIdx.x] = lc[threadIdx.x];
}

// ---------- pass B: per-type prefix over blocks + type base scan (1 tiny block) ----------
__global__ void k_offs(const int* __restrict__ hist,  // [NB][NT]
                       int* __restrict__ offs,        // [NB][NT]
                       int* __restrict__ cnt,         // [NT]
                       int* __restrict__ base) {      // [NT]
    __shared__ int tot[NT];
    int t = threadIdx.x;
    if (t < NT) {
        int run = 0;
        for (int b = 0; b < NB; ++b) { offs[b * NT + t] = run; run += hist[b * NT + t]; }
        tot[t] = run;
        cnt[t] = run;
    }
    __syncthreads();
    if (t == 0) {
        int r = 0;
        for (int tt = 0; tt < NT; ++tt) { base[tt] = r; r += tot[tt]; }
    }
}

// ---------- pass C: scatter edges to perm at precomputed offsets (no global atomics) ----------
__global__ __launch_bounds__(256) void k_fill2(const int* __restrict__ eid,
                                               const int* __restrict__ offs,
                                               const int* __restrict__ base,
                                               int* __restrict__ perm) {
    __shared__ int cur[NT];
    int b = blockIdx.x;
    if (threadIdx.x < NT) cur[threadIdx.x] = base[threadIdx.x] + offs[b * NT + threadIdx.x];
    __syncthreads();
    int e0 = b * EPB;
#pragma unroll
    for (int k = 0; k < EPB / 256 + 1; ++k) {
        int e = e0 + k * 256 + threadIdx.x;
        if (e < e0 + EPB) {
            int r = atomicAdd(&cur[eid[e]], 1);
            perm[r] = e;
        }
    }
}

// ---------- message + scatter: agg[dst] += h[src] @ W[type] (round-6 measured form) ----------
__global__ __launch_bounds__(256) void k_msg(const int* __restrict__ perm,
                                             const int* __restrict__ base,
                                             const int* __restrict__ cnt,
                                             const int* __restrict__ src,
                                             const int* __restrict__ dst,
                                             const float* __restrict__ Wt,
                                             const float* __restrict__ h,
                                             float* __restrict__ agg) {
    int t = blockIdx.x / BPT, sub = blockIdx.x % BPT;
    int lane = threadIdx.x & 31, g = threadIdx.x >> 5;
    const float* wp = Wt + t * 1024;
    float w[32];
#pragma unroll
    for (int i = 0; i < 32; ++i) w[i] = wp[i * 32 + lane];
    int n = cnt[t], b0 = base[t];
    for (int idx = sub * 8 + g; idx < n; idx += BPT * 8) {
        int e = perm[b0 + idx];
        int s = src[e], d = dst[e];
        float hv = h[s * 32 + lane];
        float acc = 0.f;
#pragma unroll
        for (int i = 0; i < 32; ++i) acc += __shfl(hv, i, 32) * w[i];
        atomicAdd(&agg[d * 32 + lane], acc);
    }
}

// ---------- GRU v4: weights resident in REGISTERS, lane = output feature ----------
// One wave (64 lanes) per block. Lane f=lane&31 owns gate rows {f, 32+f, 64+f}
// of both Wih and Whh (6x32 = 192 VGPRs, loaded once). Half-wave = one node:
// wave processes a node PAIR per iteration, grid-striding over 25000 pairs.
// Per node per lane: ONE agg float + ONE h float (coalesced 128B rows),
// __shfl(.,i,32) broadcast, 8 VALU per i. No LDS, no barrier, no weight re-reads.
__global__ __launch_bounds__(64) void k_gru(const float* __restrict__ Wih,  // [96][32]
                                            const float* __restrict__ Whh,  // [96][32]
                                            const float* __restrict__ bih,  // [96]
                                            const float* __restrict__ bhh,  // [96]
                                            const float* __restrict__ cb,   // [32]
                                            float* __restrict__ agg,
                                            float* __restrict__ h) {
    const int lane = threadIdx.x;      // block = 1 wave
    const int f = lane & 31;
    const int half = lane >> 5;

    float wiR[32], wiZ[32], wiN[32], whR[32], whZ[32], whN[32];
    {
        const float* pR = Wih + f * 32;
        const float* pZ = Wih + (32 + f) * 32;
        const float* pN = Wih + (64 + f) * 32;
        const float* qR = Whh + f * 32;
        const float* qZ = Whh + (32 + f) * 32;
        const float* qN = Whh + (64 + f) * 32;
#pragma unroll
        for (int c = 0; c < 8; ++c) {
            float4 a;
            a = ((const float4*)pR)[c]; wiR[4*c]=a.x; wiR[4*c+1]=a.y; wiR[4*c+2]=a.z; wiR[4*c+3]=a.w;
            a = ((const float4*)pZ)[c]; wiZ[4*c]=a.x; wiZ[4*c+1]=a.y; wiZ[4*c+2]=a.z; wiZ[4*c+3]=a.w;
            a = ((const float4*)pN)[c]; wiN[4*c]=a.x; wiN[4*c+1]=a.y; wiN[4*c+2]=a.z; wiN[4*c+3]=a.w;
            a = ((const float4*)qR)[c]; whR[4*c]=a.x; whR[4*c+1]=a.y; whR[4*c+2]=a.z; whR[4*c+3]=a.w;
            a = ((const float4*)qZ)[c]; whZ[4*c]=a.x; whZ[4*c+1]=a.y; whZ[4*c+2]=a.z; whZ[4*c+3]=a.w;
            a = ((const float4*)qN)[c]; whN[4*c]=a.x; whN[4*c+1]=a.y; whN[4*c+2]=a.z; whN[4*c+3]=a.w;
        }
    }
    const float bR  = bih[f] + bhh[f];
    const float bZ  = bih[32 + f] + bhh[32 + f];
    const float biN = bih[64 + f];
    const float bhN = bhh[64 + f];
    const float cbf = cb[f];

    const int stride = gridDim.x;      // one wave per block
    int p = blockIdx.x;
    float av = 0.f, hv = 0.f;
    if (p < NPAIRS) {
        int n = 2 * p + half;
        av = agg[n * 32 + f];
        hv = h[n * 32 + f];
    }
    while (p < NPAIRS) {
        // depth-1 prefetch of next pair (hides agg's L2/HBM latency under compute)
        int pn = p + stride;
        float avN = 0.f, hvN = 0.f;
        if (pn < NPAIRS) {
            int nn2 = 2 * pn + half;
            avN = agg[nn2 * 32 + f];
            hvN = h[nn2 * 32 + f];
        }
        float m = fmaxf(av + cbf, 0.f);
        float accR = 0.f, accZ = 0.f, accI = 0.f, accH = 0.f;
#pragma unroll
        for (int i = 0; i < 32; ++i) {
            float mi = __shfl(m, i, 32);
            float hi = __shfl(hv, i, 32);
            accR += mi * wiR[i] + hi * whR[i];
            accZ += mi * wiZ[i] + hi * whZ[i];
            accI += mi * wiN[i];
            accH += hi * whN[i];
        }
        float r = sigm(accR + bR);
        float z = sigm(accZ + bZ);
        float nn = tanh_f(accI + biN + r * (accH + bhN));
        float out = (1.f - z) * nn + z * hv;
        int n = 2 * p + half;
        agg[n * 32 + f] = 0.f;      // zero for next step
        h[n * 32 + f] = out;
        p = pn; av = avN; hv = hvN;
    }
}

extern "C" void kernel_launch(void* const* d_in, const int* in_sizes, int n_in,
                              void* d_out, int out_size, void* d_ws, size_t ws_size,
                              hipStream_t stream) {
    const int*   node_ids  = (const int*)d_in[0];
    const int*   edge_ids  = (const int*)d_in[1];
    const int*   src       = (const int*)d_in[2];
    const int*   dst       = (const int*)d_in[3];
    const float* node_emb  = (const float*)d_in[4];
    const float* edge_emb  = (const float*)d_in[5];
    const float* proj_W    = (const float*)d_in[6];
    const float* proj_b    = (const float*)d_in[7];
    const float* eW1       = (const float*)d_in[8];
    const float* eb1       = (const float*)d_in[9];
    const float* eW2       = (const float*)d_in[10];
    const float* eb2       = (const float*)d_in[11];
    const float* conv_bias = (const float*)d_in[12];
    const float* gWih      = (const float*)d_in[13];
    const float* gWhh      = (const float*)d_in[14];
    const float* gbih      = (const float*)d_in[15];
    const float* gbhh      = (const float*)d_in[16];

    float* h = (float*)d_out;  // [N,32] fp32 — output buffer doubles as hidden state
    char* ws = (char*)d_ws;
    float* agg  = (float*)ws;                                  // 6,400,000 B
    float* Wt   = (float*)(ws + 6400 * 1024);                  // 86,016 B
    int*   hist = (int*)(ws + 6400 * 1024 + 128 * 1024);       // NB*NT = 2100
    int*   offs = hist + NB * NT;                              // 2100
    int*   cnt  = offs + NB * NT;                              // 32
    int*   base = cnt + 32;                                    // 32
    int*   perm = base + 32;                                   // 100,000

    hipMemsetAsync(agg, 0, (size_t)N_NODES * 32 * sizeof(float), stream);

    k_proj<<<(N_NODES + 7) / 8, 256, 0, stream>>>(node_ids, node_emb, proj_W, proj_b, h);
    k_wtable<<<NT * 8, 128, 0, stream>>>(edge_emb, eW1, eb1, eW2, eb2, Wt);
    k_hist<<<NB, 256, 0, stream>>>(edge_ids, hist);
    k_offs<<<1, 64, 0, stream>>>(hist, offs, cnt, base);
    k_fill2<<<NB, 256, 0, stream>>>(edge_ids, offs, base, perm);

    for (int s = 0; s < STEPS; ++s) {
        k_msg<<<NT * BPT, 256, 0, stream>>>(perm, base, cnt, src, dst, Wt, h, agg);
        k_gru<<<GRU_WAVES, 64, 0, stream>>>(gWih, gWhh, gbih, gbhh, conv_bias, agg, h);
    }
}

// Round 9
// 539.816 us; speedup vs baseline: 2.5953x; 1.0779x over previous
//
#include <hip/hip_runtime.h>

#define N_NODES 50000
#define N_EDGES 100000
#define NT 21
#define STEPS 6
#define BPT 40    // blocks per edge-type in k_msg
#define NB 100    // blocks for counting sort
#define EPB 1000  // edges per block (NB*EPB == N_EDGES)
#define NPAIRS (N_NODES / 2)
#define GRU_WAVES 2048

// ---------- helpers ----------
__device__ __forceinline__ float sigm(float x) { return 1.f / (1.f + __expf(-x)); }
__device__ __forceinline__ float tanh_f(float x) {
    float t = __expf(2.f * fabsf(x));
    return copysignf(1.f - 2.f / (t + 1.f), x);
}

// ---------- h0 = relu(node_emb[node_ids] @ proj_W + proj_b) ----------
__global__ __launch_bounds__(256) void k_proj(const int* __restrict__ node_ids,
                                              const float* __restrict__ node_emb,
                                              const float* __restrict__ W,   // [64][32]
                                              const float* __restrict__ b,   // [32]
                                              float* __restrict__ h) {
    int lane = threadIdx.x & 31;
    int n = blockIdx.x * 8 + (threadIdx.x >> 5);
    if (n >= N_NODES) return;
    float w[64];
#pragma unroll
    for (int i = 0; i < 64; ++i) w[i] = W[i * 32 + lane];
    int id = node_ids[n];
    const float* er = node_emb + id * 64;
    float e0 = er[lane];
    float e1 = er[32 + lane];
    float acc = b[lane];
#pragma unroll
    for (int i = 0; i < 32; ++i) acc += __shfl(e0, i, 32) * w[i];
#pragma unroll
    for (int i = 0; i < 32; ++i) acc += __shfl(e1, i, 32) * w[32 + i];
    h[n * 32 + lane] = fmaxf(acc, 0.f);
}

// ---------- W table: 21 matrices, Wt[t][i][o] ----------
__global__ __launch_bounds__(128) void k_wtable(const float* __restrict__ edge_emb, // [21][16]
                                                const float* __restrict__ eW1,      // [16][128]
                                                const float* __restrict__ eb1,      // [128]
                                                const float* __restrict__ eW2,      // [128][1024]
                                                const float* __restrict__ eb2,      // [1024]
                                                float* __restrict__ Wt) {           // [21][1024]
    __shared__ float x[128];
    int t = blockIdx.x >> 3, c = blockIdx.x & 7;
    int tid = threadIdx.x;
    float acc = eb1[tid];
#pragma unroll
    for (int i = 0; i < 16; ++i) acc += edge_emb[t * 16 + i] * eW1[i * 128 + tid];
    x[tid] = fmaxf(acc, 0.f);
    __syncthreads();
    int j = c * 128 + tid;
    float a = eb2[j];
#pragma unroll 8
    for (int i = 0; i < 128; ++i) a += x[i] * eW2[i * 1024 + j];
    Wt[t * 1024 + j] = a;
}

// ---------- counting sort, pass A: per-block LDS histogram ----------
__global__ __launch_bounds__(256) void k_hist(const int* __restrict__ eid,
                                              int* __restrict__ hist) {   // [NB][NT]
    __shared__ int lc[NT];
    if (threadIdx.x < NT) lc[threadIdx.x] = 0;
    __syncthreads();
    int e0 = blockIdx.x * EPB;
#pragma unroll
    for (int k = 0; k < EPB / 256 + 1; ++k) {
        int e = e0 + k * 256 + threadIdx.x;
        if (e < e0 + EPB) atomicAdd(&lc[eid[e]], 1);
    }
    __syncthreads();
    if (threadIdx.x < NT) hist[blockIdx.x * NT + threadIdx.x] = lc[threadIdx.x];
}

// ---------- pass B: per-type prefix over blocks + type base scan (1 tiny block) ----------
__global__ void k_offs(const int* __restrict__ hist,  // [NB][NT]
                       int* __restrict__ offs,        // [NB][NT]
                       int* __restrict__ cnt,         // [NT]
                       int* __restrict__ base) {      // [NT]
    __shared__ int tot[NT];
    int t = threadIdx.x;
    if (t < NT) {
        int run = 0;
        for (int b = 0; b < NB; ++b) { offs[b * NT + t] = run; run += hist[b * NT + t]; }
        tot[t] = run;
        cnt[t] = run;
    }
    __syncthreads();
    if (t == 0) {
        int r = 0;
        for (int tt = 0; tt < NT; ++tt) { base[tt] = r; r += tot[tt]; }
    }
}

// ---------- pass C: scatter edges to perm at precomputed offsets (no global atomics) ----------
__global__ __launch_bounds__(256) void k_fill2(const int* __restrict__ eid,
                                               const int* __restrict__ offs,
                                               const int* __restrict__ base,
                                               int* __restrict__ perm) {
    __shared__ int cur[NT];
    int b = blockIdx.x;
    if (threadIdx.x < NT) cur[threadIdx.x] = base[threadIdx.x] + offs[b * NT + threadIdx.x];
    __syncthreads();
    int e0 = b * EPB;
#pragma unroll
    for (int k = 0; k < EPB / 256 + 1; ++k) {
        int e = e0 + k * 256 + threadIdx.x;
        if (e < e0 + EPB) {
            int r = atomicAdd(&cur[eid[e]], 1);
            perm[r] = e;
        }
    }
}

// ---------- message + scatter: agg[dst] += h[src] @ W[type] ----------
// v5: shfl broadcast replaced by uniform-address float4 loads of the src row.
// All 32 lanes of a half-wave issue the SAME address -> TA dedupes to one
// L1/L2 request (broadcast). Zero LDS-pipe usage.
__global__ __launch_bounds__(256) void k_msg(const int* __restrict__ perm,
                                             const int* __restrict__ base,
                                             const int* __restrict__ cnt,
                                             const int* __restrict__ src,
                                             const int* __restrict__ dst,
                                             const float* __restrict__ Wt,
                                             const float* __restrict__ h,
                                             float* __restrict__ agg) {
    int t = blockIdx.x / BPT, sub = blockIdx.x % BPT;
    int lane = threadIdx.x & 31, g = threadIdx.x >> 5;
    const float* wp = Wt + t * 1024;
    float w[32];
#pragma unroll
    for (int i = 0; i < 32; ++i) w[i] = wp[i * 32 + lane];
    int n = cnt[t], b0 = base[t];
    for (int idx = sub * 8 + g; idx < n; idx += BPT * 8) {
        int e = perm[b0 + idx];
        int s = src[e], d = dst[e];
        const float4* mp = (const float4*)(h + (size_t)s * 32);
        float acc = 0.f;
#pragma unroll
        for (int c = 0; c < 8; ++c) {
            float4 m4 = mp[c];                 // uniform per half-wave -> broadcast
            acc += m4.x * w[4 * c + 0] + m4.y * w[4 * c + 1]
                 + m4.z * w[4 * c + 2] + m4.w * w[4 * c + 3];
        }
        atomicAdd(&agg[(size_t)d * 32 + lane], acc);
    }
}

// ---------- GRU v5: register-resident weights + uniform-address row loads ----------
// launch_bounds(64,1): allow up to 512 VGPR so the 192 weight floats STAY in
// registers (v4's VGPR=132 proved the compiler reloaded them without this).
// Wave = node pair; half-wave = node; lane f owns output feature f.
// m/h rows consumed via 16 uniform float4 loads (TA broadcast), no shfl.
__global__ __launch_bounds__(64, 1) void k_gru(const float* __restrict__ Wih,  // [96][32]
                                               const float* __restrict__ Whh,  // [96][32]
                                               const float* __restrict__ bih,  // [96]
                                               const float* __restrict__ bhh,  // [96]
                                               const float* __restrict__ cb,   // [32]
                                               float* __restrict__ agg,
                                               float* __restrict__ h) {
    const int lane = threadIdx.x;      // block = 1 wave
    const int f = lane & 31;
    const int half = lane >> 5;

    float wiR[32], wiZ[32], wiN[32], whR[32], whZ[32], whN[32];
    {
        const float* pR = Wih + f * 32;
        const float* pZ = Wih + (32 + f) * 32;
        const float* pN = Wih + (64 + f) * 32;
        const float* qR = Whh + f * 32;
        const float* qZ = Whh + (32 + f) * 32;
        const float* qN = Whh + (64 + f) * 32;
#pragma unroll
        for (int c = 0; c < 8; ++c) {
            float4 a;
            a = ((const float4*)pR)[c]; wiR[4*c]=a.x; wiR[4*c+1]=a.y; wiR[4*c+2]=a.z; wiR[4*c+3]=a.w;
            a = ((const float4*)pZ)[c]; wiZ[4*c]=a.x; wiZ[4*c+1]=a.y; wiZ[4*c+2]=a.z; wiZ[4*c+3]=a.w;
            a = ((const float4*)pN)[c]; wiN[4*c]=a.x; wiN[4*c+1]=a.y; wiN[4*c+2]=a.z; wiN[4*c+3]=a.w;
            a = ((const float4*)qR)[c]; whR[4*c]=a.x; whR[4*c+1]=a.y; whR[4*c+2]=a.z; whR[4*c+3]=a.w;
            a = ((const float4*)qZ)[c]; whZ[4*c]=a.x; whZ[4*c+1]=a.y; whZ[4*c+2]=a.z; whZ[4*c+3]=a.w;
            a = ((const float4*)qN)[c]; whN[4*c]=a.x; whN[4*c+1]=a.y; whN[4*c+2]=a.z; whN[4*c+3]=a.w;
        }
    }
    const float bR  = bih[f] + bhh[f];
    const float bZ  = bih[32 + f] + bhh[32 + f];
    const float biN = bih[64 + f];
    const float bhN = bhh[64 + f];

    const int stride = gridDim.x;
    for (int p = blockIdx.x; p < NPAIRS; p += stride) {
        int n = 2 * p + half;
        const float4* ap = (const float4*)(agg + (size_t)n * 32);
        const float4* hp = (const float4*)(h + (size_t)n * 32);
        float accR = 0.f, accZ = 0.f, accI = 0.f, accH = 0.f;
#pragma unroll
        for (int c = 0; c < 8; ++c) {
            float4 a4 = ap[c];                      // uniform per half -> broadcast
            float4 h4 = hp[c];
            float4 cb4 = ((const float4*)cb)[c];    // const, scalarizable
            float mm0 = fmaxf(a4.x + cb4.x, 0.f);
            float mm1 = fmaxf(a4.y + cb4.y, 0.f);
            float mm2 = fmaxf(a4.z + cb4.z, 0.f);
            float mm3 = fmaxf(a4.w + cb4.w, 0.f);
            int i = 4 * c;
            accR += mm0 * wiR[i]     + h4.x * whR[i];
            accZ += mm0 * wiZ[i]     + h4.x * whZ[i];
            accI += mm0 * wiN[i];      accH += h4.x * whN[i];
            accR += mm1 * wiR[i + 1] + h4.y * whR[i + 1];
            accZ += mm1 * wiZ[i + 1] + h4.y * whZ[i + 1];
            accI += mm1 * wiN[i + 1];  accH += h4.y * whN[i + 1];
            accR += mm2 * wiR[i + 2] + h4.z * whR[i + 2];
            accZ += mm2 * wiZ[i + 2] + h4.z * whZ[i + 2];
            accI += mm2 * wiN[i + 2];  accH += h4.z * whN[i + 2];
            accR += mm3 * wiR[i + 3] + h4.w * whR[i + 3];
            accZ += mm3 * wiZ[i + 3] + h4.w * whZ[i + 3];
            accI += mm3 * wiN[i + 3];  accH += h4.w * whN[i + 3];
        }
        float hf = h[(size_t)n * 32 + f];   // own value, L1-hot (row just fetched)
        float r = sigm(accR + bR);
        float z = sigm(accZ + bZ);
        float nn = tanh_f(accI + biN + r * (accH + bhN));
        float out = (1.f - z) * nn + z * hf;
        agg[(size_t)n * 32 + f] = 0.f;      // zero for next step (after all loads)
        h[(size_t)n * 32 + f] = out;
    }
}

extern "C" void kernel_launch(void* const* d_in, const int* in_sizes, int n_in,
                              void* d_out, int out_size, void* d_ws, size_t ws_size,
                              hipStream_t stream) {
    const int*   node_ids  = (const int*)d_in[0];
    const int*   edge_ids  = (const int*)d_in[1];
    const int*   src       = (const int*)d_in[2];
    const int*   dst       = (const int*)d_in[3];
    const float* node_emb  = (const float*)d_in[4];
    const float* edge_emb  = (const float*)d_in[5];
    const float* proj_W    = (const float*)d_in[6];
    const float* proj_b    = (const float*)d_in[7];
    const float* eW1       = (const float*)d_in[8];
    const float* eb1       = (const float*)d_in[9];
    const float* eW2       = (const float*)d_in[10];
    const float* eb2       = (const float*)d_in[11];
    const float* conv_bias = (const float*)d_in[12];
    const float* gWih      = (const float*)d_in[13];
    const float* gWhh      = (const float*)d_in[14];
    const float* gbih      = (const float*)d_in[15];
    const float* gbhh      = (const float*)d_in[16];

    float* h = (float*)d_out;  // [N,32] fp32 — output buffer doubles as hidden state
    char* ws = (char*)d_ws;
    float* agg  = (float*)ws;                                  // 6,400,000 B
    float* Wt   = (float*)(ws + 6400 * 1024);                  // 86,016 B
    int*   hist = (int*)(ws + 6400 * 1024 + 128 * 1024);       // NB*NT = 2100
    int*   offs = hist + NB * NT;                              // 2100
    int*   cnt  = offs + NB * NT;                              // 32
    int*   base = cnt + 32;                                    // 32
    int*   perm = base + 32;                                   // 100,000

    hipMemsetAsync(agg, 0, (size_t)N_NODES * 32 * sizeof(float), stream);

    k_proj<<<(N_NODES + 7) / 8, 256, 0, stream>>>(node_ids, node_emb, proj_W, proj_b, h);
    k_wtable<<<NT * 8, 128, 0, stream>>>(edge_emb, eW1, eb1, eW2, eb2, Wt);
    k_hist<<<NB, 256, 0, stream>>>(edge_ids, hist);
    k_offs<<<1, 64, 0, stream>>>(hist, offs, cnt, base);
    k_fill2<<<NB, 256, 0, stream>>>(edge_ids, offs, base, perm);

    for (int s = 0; s < STEPS; ++s) {
        k_msg<<<NT * BPT, 256, 0, stream>>>(perm, base, cnt, src, dst, Wt, h, agg);
        k_gru<<<GRU_WAVES, 64, 0, stream>>>(gWih, gWhh, gbih, gbhh, conv_bias, agg, h);
    }
}

// Round 10
// 519.133 us; speedup vs baseline: 2.6987x; 1.0398x over previous
//
#include <hip/hip_runtime.h>

#define N_NODES 50000
#define N_EDGES 100000
#define NT 21
#define STEPS 6
#define BPT 40    // blocks per edge-type in k_msg
#define NB 100    // blocks for counting sort
#define EPB 1000  // edges per block (NB*EPB == N_EDGES)
#define NPAIRS (N_NODES / 2)
#define GRU_WAVES 2048

// ---------- helpers ----------
__device__ __forceinline__ float sigm(float x) { return 1.f / (1.f + __expf(-x)); }
__device__ __forceinline__ float tanh_f(float x) {
    float t = __expf(2.f * fabsf(x));
    return copysignf(1.f - 2.f / (t + 1.f), x);
}

// ---------- h0 = relu(node_emb[node_ids] @ proj_W + proj_b) ----------
__global__ __launch_bounds__(256) void k_proj(const int* __restrict__ node_ids,
                                              const float* __restrict__ node_emb,
                                              const float* __restrict__ W,   // [64][32]
                                              const float* __restrict__ b,   // [32]
                                              float* __restrict__ h) {
    int lane = threadIdx.x & 31;
    int n = blockIdx.x * 8 + (threadIdx.x >> 5);
    if (n >= N_NODES) return;
    float w[64];
#pragma unroll
    for (int i = 0; i < 64; ++i) w[i] = W[i * 32 + lane];
    int id = node_ids[n];
    const float* er = node_emb + id * 64;
    float e0 = er[lane];
    float e1 = er[32 + lane];
    float acc = b[lane];
#pragma unroll
    for (int i = 0; i < 32; ++i) acc += __shfl(e0, i, 32) * w[i];
#pragma unroll
    for (int i = 0; i < 32; ++i) acc += __shfl(e1, i, 32) * w[32 + i];
    h[n * 32 + lane] = fmaxf(acc, 0.f);
}

// ---------- W table: 21 matrices, Wt[t][i][o] ----------
__global__ __launch_bounds__(128) void k_wtable(const float* __restrict__ edge_emb, // [21][16]
                                                const float* __restrict__ eW1,      // [16][128]
                                                const float* __restrict__ eb1,      // [128]
                                                const float* __restrict__ eW2,      // [128][1024]
                                                const float* __restrict__ eb2,      // [1024]
                                                float* __restrict__ Wt) {           // [21][1024]
    __shared__ float x[128];
    int t = blockIdx.x >> 3, c = blockIdx.x & 7;
    int tid = threadIdx.x;
    float acc = eb1[tid];
#pragma unroll
    for (int i = 0; i < 16; ++i) acc += edge_emb[t * 16 + i] * eW1[i * 128 + tid];
    x[tid] = fmaxf(acc, 0.f);
    __syncthreads();
    int j = c * 128 + tid;
    float a = eb2[j];
#pragma unroll 8
    for (int i = 0; i < 128; ++i) a += x[i] * eW2[i * 1024 + j];
    Wt[t * 1024 + j] = a;
}

// ---------- counting sort, pass A: per-block LDS histogram ----------
__global__ __launch_bounds__(256) void k_hist(const int* __restrict__ eid,
                                              int* __restrict__ hist) {   // [NB][NT]
    __shared__ int lc[NT];
    if (threadIdx.x < NT) lc[threadIdx.x] = 0;
    __syncthreads();
    int e0 = blockIdx.x * EPB;
#pragma unroll
    for (int k = 0; k < EPB / 256 + 1; ++k) {
        int e = e0 + k * 256 + threadIdx.x;
        if (e < e0 + EPB) atomicAdd(&lc[eid[e]], 1);
    }
    __syncthreads();
    if (threadIdx.x < NT) hist[blockIdx.x * NT + threadIdx.x] = lc[threadIdx.x];
}

// ---------- pass B: per-type prefix over blocks + type base scan (1 tiny block) ----------
__global__ void k_offs(const int* __restrict__ hist,  // [NB][NT]
                       int* __restrict__ offs,        // [NB][NT]
                       int* __restrict__ cnt,         // [NT]
                       int* __restrict__ base) {      // [NT]
    __shared__ int tot[NT];
    int t = threadIdx.x;
    if (t < NT) {
        int run = 0;
        for (int b = 0; b < NB; ++b) { offs[b * NT + t] = run; run += hist[b * NT + t]; }
        tot[t] = run;
        cnt[t] = run;
    }
    __syncthreads();
    if (t == 0) {
        int r = 0;
        for (int tt = 0; tt < NT; ++tt) { base[tt] = r; r += tot[tt]; }
    }
}

// ---------- pass C: scatter edges to perm at precomputed offsets (no global atomics) ----------
__global__ __launch_bounds__(256) void k_fill2(const int* __restrict__ eid,
                                               const int* __restrict__ offs,
                                               const int* __restrict__ base,
                                               int* __restrict__ perm) {
    __shared__ int cur[NT];
    int b = blockIdx.x;
    if (threadIdx.x < NT) cur[threadIdx.x] = base[threadIdx.x] + offs[b * NT + threadIdx.x];
    __syncthreads();
    int e0 = b * EPB;
#pragma unroll
    for (int k = 0; k < EPB / 256 + 1; ++k) {
        int e = e0 + k * 256 + threadIdx.x;
        if (e < e0 + EPB) {
            int r = atomicAdd(&cur[eid[e]], 1);
            perm[r] = e;
        }
    }
}

// ---------- message + scatter: agg[dst] += h[src] @ W[type] ----------
// round-6 MEASURED form (shfl broadcast): uniform-load variant regressed ~16us.
__global__ __launch_bounds__(256) void k_msg(const int* __restrict__ perm,
                                             const int* __restrict__ base,
                                             const int* __restrict__ cnt,
                                             const int* __restrict__ src,
                                             const int* __restrict__ dst,
                                             const float* __restrict__ Wt,
                                             const float* __restrict__ h,
                                             float* __restrict__ agg) {
    int t = blockIdx.x / BPT, sub = blockIdx.x % BPT;
    int lane = threadIdx.x & 31, g = threadIdx.x >> 5;
    const float* wp = Wt + t * 1024;
    float w[32];
#pragma unroll
    for (int i = 0; i < 32; ++i) w[i] = wp[i * 32 + lane];
    int n = cnt[t], b0 = base[t];
    for (int idx = sub * 8 + g; idx < n; idx += BPT * 8) {
        int e = perm[b0 + idx];
        int s = src[e], d = dst[e];
        float hv = h[s * 32 + lane];
        float acc = 0.f;
#pragma unroll
        for (int i = 0; i < 32; ++i) acc += __shfl(hv, i, 32) * w[i];
        atomicAdd(&agg[d * 32 + lane], acc);
    }
}

// ---------- GRU v6: register-resident weights FORCED via inline-asm pins ----------
// v4/v5 post-mortem: compiler rematerialized the 192 weight loads inside the
// grid-stride loop (VGPR=132/140), paying a 128B-strided 32-line gather every
// iteration (~45us). The empty asm "+v" makes each weight the result of an
// opaque op -> LLVM cannot re-execute the load; RA must keep them in VGPRs.
// launch_bounds(64,2): cap 256 VGPR (192 weights + ~50 working), 2 waves/SIMD.
// Wave = node pair; half-wave = node; lane f owns output feature f.
// m/h rows via 16 uniform-address float4 loads (TA broadcast), no shfl.
__global__ __launch_bounds__(64, 2) void k_gru(const float* __restrict__ Wih,  // [96][32]
                                               const float* __restrict__ Whh,  // [96][32]
                                               const float* __restrict__ bih,  // [96]
                                               const float* __restrict__ bhh,  // [96]
                                               const float* __restrict__ cb,   // [32]
                                               float* __restrict__ agg,
                                               float* __restrict__ h) {
    const int lane = threadIdx.x;      // block = 1 wave
    const int f = lane & 31;
    const int half = lane >> 5;

    float wiR[32], wiZ[32], wiN[32], whR[32], whZ[32], whN[32];
    {
        const float* pR = Wih + f * 32;
        const float* pZ = Wih + (32 + f) * 32;
        const float* pN = Wih + (64 + f) * 32;
        const float* qR = Whh + f * 32;
        const float* qZ = Whh + (32 + f) * 32;
        const float* qN = Whh + (64 + f) * 32;
#pragma unroll
        for (int c = 0; c < 8; ++c) {
            float4 a;
            a = ((const float4*)pR)[c]; wiR[4*c]=a.x; wiR[4*c+1]=a.y; wiR[4*c+2]=a.z; wiR[4*c+3]=a.w;
            a = ((const float4*)pZ)[c]; wiZ[4*c]=a.x; wiZ[4*c+1]=a.y; wiZ[4*c+2]=a.z; wiZ[4*c+3]=a.w;
            a = ((const float4*)pN)[c]; wiN[4*c]=a.x; wiN[4*c+1]=a.y; wiN[4*c+2]=a.z; wiN[4*c+3]=a.w;
            a = ((const float4*)qR)[c]; whR[4*c]=a.x; whR[4*c+1]=a.y; whR[4*c+2]=a.z; whR[4*c+3]=a.w;
            a = ((const float4*)qZ)[c]; whZ[4*c]=a.x; whZ[4*c+1]=a.y; whZ[4*c+2]=a.z; whZ[4*c+3]=a.w;
            a = ((const float4*)qN)[c]; whN[4*c]=a.x; whN[4*c+1]=a.y; whN[4*c+2]=a.z; whN[4*c+3]=a.w;
        }
    }
    // pin: forbid rematerialization of the weight loads inside the loop
#pragma unroll
    for (int i = 0; i < 32; ++i) {
        asm volatile("" : "+v"(wiR[i]), "+v"(wiZ[i]), "+v"(wiN[i]),
                          "+v"(whR[i]), "+v"(whZ[i]), "+v"(whN[i]));
    }

    const float bR  = bih[f] + bhh[f];
    const float bZ  = bih[32 + f] + bhh[32 + f];
    const float biN = bih[64 + f];
    const float bhN = bhh[64 + f];

    const int stride = gridDim.x;
    for (int p = blockIdx.x; p < NPAIRS; p += stride) {
        int n = 2 * p + half;
        const float4* ap = (const float4*)(agg + (size_t)n * 32);
        const float4* hp = (const float4*)(h + (size_t)n * 32);
        float accR = 0.f, accZ = 0.f, accI = 0.f, accH = 0.f;
#pragma unroll
        for (int c = 0; c < 8; ++c) {
            float4 a4 = ap[c];                      // uniform per half -> broadcast
            float4 h4 = hp[c];
            float4 cb4 = ((const float4*)cb)[c];    // uniform, scalar-promoted
            float mm0 = fmaxf(a4.x + cb4.x, 0.f);
            float mm1 = fmaxf(a4.y + cb4.y, 0.f);
            float mm2 = fmaxf(a4.z + cb4.z, 0.f);
            float mm3 = fmaxf(a4.w + cb4.w, 0.f);
            int i = 4 * c;
            accR += mm0 * wiR[i]     + h4.x * whR[i];
            accZ += mm0 * wiZ[i]     + h4.x * whZ[i];
            accI += mm0 * wiN[i];      accH += h4.x * whN[i];
            accR += mm1 * wiR[i + 1] + h4.y * whR[i + 1];
            accZ += mm1 * wiZ[i + 1] + h4.y * whZ[i + 1];
            accI += mm1 * wiN[i + 1];  accH += h4.y * whN[i + 1];
            accR += mm2 * wiR[i + 2] + h4.z * whR[i + 2];
            accZ += mm2 * wiZ[i + 2] + h4.z * whZ[i + 2];
            accI += mm2 * wiN[i + 2];  accH += h4.z * whN[i + 2];
            accR += mm3 * wiR[i + 3] + h4.w * whR[i + 3];
            accZ += mm3 * wiZ[i + 3] + h4.w * whZ[i + 3];
            accI += mm3 * wiN[i + 3];  accH += h4.w * whN[i + 3];
        }
        float hf = h[(size_t)n * 32 + f];   // own value, L1-hot (row just fetched)
        float r = sigm(accR + bR);
        float z = sigm(accZ + bZ);
        float nn = tanh_f(accI + biN + r * (accH + bhN));
        float out = (1.f - z) * nn + z * hf;
        agg[(size_t)n * 32 + f] = 0.f;      // zero for next step (after all loads)
        h[(size_t)n * 32 + f] = out;
    }
}

extern "C" void kernel_launch(void* const* d_in, const int* in_sizes, int n_in,
                              void* d_out, int out_size, void* d_ws, size_t ws_size,
                              hipStream_t stream) {
    const int*   node_ids  = (const int*)d_in[0];
    const int*   edge_ids  = (const int*)d_in[1];
    const int*   src       = (const int*)d_in[2];
    const int*   dst       = (const int*)d_in[3];
    const float* node_emb  = (const float*)d_in[4];
    const float* edge_emb  = (const float*)d_in[5];
    const float* proj_W    = (const float*)d_in[6];
    const float* proj_b    = (const float*)d_in[7];
    const float* eW1       = (const float*)d_in[8];
    const float* eb1       = (const float*)d_in[9];
    const float* eW2       = (const float*)d_in[10];
    const float* eb2       = (const float*)d_in[11];
    const float* conv_bias = (const float*)d_in[12];
    const float* gWih      = (const float*)d_in[13];
    const float* gWhh      = (const float*)d_in[14];
    const float* gbih      = (const float*)d_in[15];
    const float* gbhh      = (const float*)d_in[16];

    float* h = (float*)d_out;  // [N,32] fp32 — output buffer doubles as hidden state
    char* ws = (char*)d_ws;
    float* agg  = (float*)ws;                                  // 6,400,000 B
    float* Wt   = (float*)(ws + 6400 * 1024);                  // 86,016 B
    int*   hist = (int*)(ws + 6400 * 1024 + 128 * 1024);       // NB*NT = 2100
    int*   offs = hist + NB * NT;                              // 2100
    int*   cnt  = offs + NB * NT;                              // 32
    int*   base = cnt + 32;                                    // 32
    int*   perm = base + 32;                                   // 100,000

    hipMemsetAsync(agg, 0, (size_t)N_NODES * 32 * sizeof(float), stream);

    k_proj<<<(N_NODES + 7) / 8, 256, 0, stream>>>(node_ids, node_emb, proj_W, proj_b, h);
    k_wtable<<<NT * 8, 128, 0, stream>>>(edge_emb, eW1, eb1, eW2, eb2, Wt);
    k_hist<<<NB, 256, 0, stream>>>(edge_ids, hist);
    k_offs<<<1, 64, 0, stream>>>(hist, offs, cnt, base);
    k_fill2<<<NB, 256, 0, stream>>>(edge_ids, offs, base, perm);

    for (int s = 0; s < STEPS; ++s) {
        k_msg<<<NT * BPT, 256, 0, stream>>>(perm, base, cnt, src, dst, Wt, h, agg);
        k_gru<<<GRU_WAVES, 64, 0, stream>>>(gWih, gWhh, gbih, gbhh, conv_bias, agg, h);
    }
}